// Round 3
// baseline (724.531 us; speedup 1.0000x reference)
//
#include <hip/hip_runtime.h>

// AfmoeAttention on MI355X (gfx950), round 3.
// Change vs r2: attention restructured — static-max softmax (scores provably
// |s|<=8 via RMSNorm), direct global->register fragment loads for Q/K/V
// (no staging, no __syncthreads in the whole kernel), LDS only for the
// wave-private P C->A layout round-trip (16 KB), launch_bounds(256,3).

#define LOG2E 1.44269504088896340736f

typedef __attribute__((ext_vector_type(4))) float f32x4;
typedef __attribute__((ext_vector_type(8))) short bf16x8;   // 8 x bf16 (4 VGPRs)

__device__ __forceinline__ float bf2f(unsigned short u) {
  union { unsigned u; float f; } x; x.u = ((unsigned)u) << 16; return x.f;
}
__device__ __forceinline__ unsigned short f2bf(float f) {
  union { float f; unsigned u; } x; x.f = f;
  unsigned r = x.u + 0x7fffu + ((x.u >> 16) & 1u);   // RNE
  return (unsigned short)(r >> 16);
}

// async global->LDS, 16B per lane. LDS dest = wave-uniform base + lane*16.
__device__ __forceinline__ void async16(void* lds, const void* g) {
  __builtin_amdgcn_global_load_lds(
      (const __attribute__((address_space(1))) unsigned*)g,
      (__attribute__((address_space(3))) unsigned*)lds, 16, 0, 0);
}

// ---------------------------------------------------------------- cvt kernel
__global__ __launch_bounds__(256) void cvt_f32_bf16(
    const float* __restrict__ src, unsigned short* __restrict__ dst, int n4) {
  int i = blockIdx.x * 256 + threadIdx.x;
  if (i >= n4) return;
  float4 v = reinterpret_cast<const float4*>(src)[i];
  ushort4 u;
  u.x = f2bf(v.x); u.y = f2bf(v.y); u.z = f2bf(v.z); u.w = f2bf(v.w);
  reinterpret_cast<ushort4*>(dst)[i] = u;
}

// ------------------------------------------------------------- GEMM template
// C[M,N] = A[M,K] @ W[N,K]^T, 128x128 tile, BK=32, 4 waves each 64x64.
template <typename CT>
__device__ __forceinline__ void gemm128(
    const unsigned short* __restrict__ A, const unsigned short* __restrict__ W,
    CT* __restrict__ C, int m0, int n0, int ldc, int K,
    unsigned short* As, unsigned short* Bs) {
  const int tid = threadIdx.x;
  const int w = tid >> 6, l = tid & 63, quad = l >> 4, l16 = l & 15;
  const int wm = (w & 1) * 64, wn = (w >> 1) * 64;

  f32x4 acc[4][4];
  const f32x4 Z4 = {0.f, 0.f, 0.f, 0.f};
#pragma unroll
  for (int i = 0; i < 4; i++)
#pragma unroll
    for (int j = 0; j < 4; j++) acc[i][j] = Z4;

  const int srow = tid >> 2;            // 0..63
  const int scol = (tid & 3) * 8;       // elem offset in K
  const unsigned short* gA = A + (size_t)(m0 + srow) * K + scol;
  const unsigned short* gB = W + (size_t)(n0 + srow) * K + scol;
  unsigned short* lA = As + tid * 8;    // byte offset tid*16
  unsigned short* lB = Bs + tid * 8;

  for (int kb = 0; kb < K; kb += 32) {
    async16(lA,        gA + kb);
    async16(lA + 2048, gA + (size_t)64 * K + kb);
    async16(lB,        gB + kb);
    async16(lB + 2048, gB + (size_t)64 * K + kb);
    __syncthreads();   // waits vmcnt(0): async LDS writes landed

    bf16x8 af[4], bf[4];
#pragma unroll
    for (int mt = 0; mt < 4; mt++)
      af[mt] = *(const bf16x8*)&As[(wm + mt * 16 + l16) * 32 + quad * 8];
#pragma unroll
    for (int nt = 0; nt < 4; nt++)
      bf[nt] = *(const bf16x8*)&Bs[(wn + nt * 16 + l16) * 32 + quad * 8];
#pragma unroll
    for (int mt = 0; mt < 4; mt++)
#pragma unroll
      for (int nt = 0; nt < 4; nt++)
        acc[mt][nt] = __builtin_amdgcn_mfma_f32_16x16x32_bf16(
            af[mt], bf[nt], acc[mt][nt], 0, 0, 0);
    __syncthreads();   // all reads done before next tile's staging
  }

  // C/D layout: col = lane&15, row = quad*4 + reg
#pragma unroll
  for (int mt = 0; mt < 4; mt++)
#pragma unroll
    for (int nt = 0; nt < 4; nt++) {
      int row = m0 + wm + mt * 16 + quad * 4;
      int col = n0 + wn + nt * 16 + l16;
#pragma unroll
      for (int r = 0; r < 4; r++) {
        if constexpr (sizeof(CT) == 2)
          C[(size_t)(row + r) * ldc + col] = f2bf(acc[mt][nt][r]);
        else
          C[(size_t)(row + r) * ldc + col] = acc[mt][nt][r];
      }
    }
}

__global__ __launch_bounds__(256) void gemm_qkvg(
    const unsigned short* __restrict__ X,
    const unsigned short* __restrict__ Wq, const unsigned short* __restrict__ Wk,
    const unsigned short* __restrict__ Wv, const unsigned short* __restrict__ Wg,
    unsigned short* __restrict__ Qr, unsigned short* __restrict__ Kr,
    unsigned short* __restrict__ Vr, unsigned short* __restrict__ Gr) {
  __shared__ __attribute__((aligned(16))) unsigned short As[128 * 32];
  __shared__ __attribute__((aligned(16))) unsigned short Bs[128 * 32];
  int ny = blockIdx.y;
  const unsigned short* W; unsigned short* C; int n0, ldc;
  if (ny < 16)      { W = Wq; C = Qr; n0 = ny * 128;        ldc = 2048; }
  else if (ny < 18) { W = Wk; C = Kr; n0 = (ny - 16) * 128; ldc = 256;  }
  else if (ny < 20) { W = Wv; C = Vr; n0 = (ny - 18) * 128; ldc = 256;  }
  else              { W = Wg; C = Gr; n0 = (ny - 20) * 128; ldc = 2048; }
  gemm128<unsigned short>(X, W, C, blockIdx.x * 128, n0, ldc, 2048, As, Bs);
}

__global__ __launch_bounds__(256) void gemm_out_k(
    const unsigned short* __restrict__ A, const unsigned short* __restrict__ W,
    float* __restrict__ C) {
  __shared__ __attribute__((aligned(16))) unsigned short As[128 * 32];
  __shared__ __attribute__((aligned(16))) unsigned short Bs[128 * 32];
  gemm128<float>(A, W, C, blockIdx.x * 128, blockIdx.y * 128, 2048, 2048, As, Bs);
}

// ------------------------------------------------------ RMSNorm+RoPE+transpose
__global__ __launch_bounds__(256) void prep_qkv(
    const unsigned short* __restrict__ Qr, const unsigned short* __restrict__ Kr,
    const unsigned short* __restrict__ Vr,
    const float* __restrict__ cosb, const float* __restrict__ sinb,
    const float* __restrict__ qg, const float* __restrict__ kg,
    unsigned short* __restrict__ Qn, unsigned short* __restrict__ Kn,
    unsigned short* __restrict__ Vt) {
  int idx = blockIdx.x * 4 + (threadIdx.x >> 6);   // global unit index
  int d = threadIdx.x & 63;
  int token = idx / 40;
  int unit = idx - token * 40;
  int b = token >> 11, s = token & 2047;

  if (unit >= 36) {   // V transpose (scattered 2B stores, small total)
    int kvh = unit - 36;
    Vt[((size_t)(b * 4 + kvh) * 64 + d) * 2048 + s] =
        Vr[(size_t)token * 256 + kvh * 64 + d];
    return;
  }
  const unsigned short* src; const float* gamma; float scale; unsigned short* dst;
  if (unit < 32) {
    src = Qr + (size_t)token * 2048 + unit * 64;
    gamma = qg; scale = 0.125f;               // 1/sqrt(D)
    dst = Qn + ((size_t)(b * 32 + unit) * 2048 + s) * 64;
  } else {
    int kvh = unit - 32;
    src = Kr + (size_t)token * 256 + kvh * 64;
    gamma = kg; scale = 1.0f;
    dst = Kn + ((size_t)(b * 4 + kvh) * 2048 + s) * 64;
  }
  float x = bf2f(src[d]);
  float ss = x * x;
#pragma unroll
  for (int off = 32; off >= 1; off >>= 1) ss += __shfl_xor(ss, off);
  float rr = rsqrtf(ss * (1.0f / 64.0f) + 1e-6f);
  float xn = x * rr * gamma[d];
  float other = __shfl_xor(xn, 32);           // partner at d^32
  float rot = (d < 32) ? -other : other;      // rotate_half
  size_t cs = (size_t)(b * 2048 + s) * 64 + d;
  dst[d] = f2bf((xn * cosb[cs] + rot * sinb[cs]) * scale);
}

// ---------------------------------------------------------- flash attention
// grid: (S/128, B*NH). 4 waves, each owns 32 Q rows, fully independent.
// Static-max softmax: scores bounded |s|<=8 (RMSNorm => ||q||=1 after /8
// fold, ||k||=8), so exp2(s*log2e) <= 2^11.6 — no max tracking needed.
// All Q/K/V fragments loaded DIRECTLY global->VGPR (16B chunks match MFMA
// operand layout; Vt pre-transposed for this). LDS holds only the per-wave
// P tile (C-layout -> A-layout round-trip), XOR-swizzled. No barriers.
__global__ __launch_bounds__(256, 3) void attn(
    const unsigned short* __restrict__ Qn, const unsigned short* __restrict__ Kn,
    const unsigned short* __restrict__ Vt, const unsigned short* __restrict__ gate,
    unsigned short* __restrict__ act) {
  __shared__ __attribute__((aligned(16))) unsigned short Ps[4 * 2048];  // 16 KB

  const int tid = threadIdx.x, w = tid >> 6, l = tid & 63;
  const int quad = l >> 4, l16 = l & 15, l7 = l16 & 7;
  const int bh = blockIdx.y, b = bh >> 5, h = bh & 31, kvh = h >> 3;
  const int q0 = blockIdx.x * 128;

  const unsigned short* Qg = Qn + ((size_t)(b * 32 + h) * 2048 + q0) * 64;
  const unsigned short* Kg = Kn + (size_t)(b * 4 + kvh) * 2048 * 64;
  const unsigned short* Vg = Vt + (size_t)(b * 4 + kvh) * 64 * 2048;
  unsigned short* Pw = Ps + w * 2048;   // wave-private [32 q][64 kv], swizzled

  // Q fragments, direct load (A-operand: m=l16, k=quad*8+j)
  bf16x8 qf[2][2];
#pragma unroll
  for (int mt = 0; mt < 2; mt++)
#pragma unroll
    for (int ks = 0; ks < 2; ks++)
      qf[mt][ks] = *(const bf16x8*)(Qg + (size_t)(w * 32 + mt * 16 + l16) * 64 +
                                    ks * 32 + quad * 8);

  const f32x4 Z4 = {0.f, 0.f, 0.f, 0.f};
  f32x4 O[2][4];
  float lp[2][4];
#pragma unroll
  for (int mt = 0; mt < 2; mt++) {
#pragma unroll
    for (int nt = 0; nt < 4; nt++) O[mt][nt] = Z4;
#pragma unroll
    for (int r = 0; r < 4; r++) lp[mt][r] = 0.f;
  }

  for (int kt = 0; kt < 16; kt++) {
#pragma unroll
    for (int half = 0; half < 2; half++) {
      const int sh = kt * 128 + half * 64;

      // ---- S = Q K^T over this kv-64 half (K frags direct from global)
      f32x4 sc[2][4];
#pragma unroll
      for (int mt = 0; mt < 2; mt++)
#pragma unroll
        for (int nt = 0; nt < 4; nt++) sc[mt][nt] = Z4;
#pragma unroll
      for (int nt = 0; nt < 4; nt++) {
        const unsigned short* kr = Kg + (size_t)(sh + nt * 16 + l16) * 64;
        bf16x8 kf0 = *(const bf16x8*)(kr + quad * 8);
        bf16x8 kf1 = *(const bf16x8*)(kr + 32 + quad * 8);
#pragma unroll
        for (int mt = 0; mt < 2; mt++) {
          sc[mt][nt] = __builtin_amdgcn_mfma_f32_16x16x32_bf16(qf[mt][0], kf0, sc[mt][nt], 0, 0, 0);
          sc[mt][nt] = __builtin_amdgcn_mfma_f32_16x16x32_bf16(qf[mt][1], kf1, sc[mt][nt], 0, 0, 0);
        }
      }

      // ---- V fragments for this half (issued early to hide latency)
      bf16x8 vf[2][4];
#pragma unroll
      for (int ks2 = 0; ks2 < 2; ks2++)
#pragma unroll
        for (int nt2 = 0; nt2 < 4; nt2++)
          vf[ks2][nt2] = *(const bf16x8*)(Vg + (size_t)(nt2 * 16 + l16) * 2048 +
                                          sh + ks2 * 32 + quad * 8);

      // ---- p = exp(s), truncate to bf16; l summed from the SAME truncated
      // values (normalization-consistent). Store P swizzled to LDS.
#pragma unroll
      for (int mt = 0; mt < 2; mt++)
#pragma unroll
        for (int nt = 0; nt < 4; nt++)
#pragma unroll
          for (int r = 0; r < 4; r++) {
            float p = __builtin_amdgcn_exp2f(sc[mt][nt][r] * LOG2E);
            union { float f; unsigned u; } x; x.f = p;
            union { unsigned u; float f; } t; t.u = x.u & 0xffff0000u;
            lp[mt][r] += t.f;
            int q = mt * 16 + quad * 4 + r;
            int kv = nt * 16 + l16;
            int phys = (kv >> 3) ^ (q & 7);
            Pw[q * 64 + phys * 8 + (kv & 7)] = (unsigned short)(x.u >> 16);
          }
      // (same-wave LDS RAW: compiler inserts lgkmcnt waits; DS pipe in-order)

      // ---- O += P V
#pragma unroll
      for (int ks2 = 0; ks2 < 2; ks2++) {
        bf16x8 pf[2];
#pragma unroll
        for (int mt = 0; mt < 2; mt++) {
          int q = mt * 16 + l16;
          int c = (ks2 * 4 + quad) ^ (q & 7);
          pf[mt] = *(const bf16x8*)&Pw[q * 64 + c * 8];
        }
#pragma unroll
        for (int nt2 = 0; nt2 < 4; nt2++)
#pragma unroll
          for (int mt = 0; mt < 2; mt++)
            O[mt][nt2] = __builtin_amdgcn_mfma_f32_16x16x32_bf16(
                pf[mt], vf[ks2][nt2], O[mt][nt2], 0, 0, 0);
      }
    }
  }

  // ---- final l reduction across the 16-lane column groups (once)
#pragma unroll
  for (int mt = 0; mt < 2; mt++)
#pragma unroll
    for (int r = 0; r < 4; r++) {
      float s = lp[mt][r];
#pragma unroll
      for (int off = 1; off < 16; off <<= 1) s += __shfl_xor(s, off);
      lp[mt][r] = s;
    }

  // ---- epilogue: O/l * sigmoid(gate) -> act[b][s][h*64+d]
#pragma unroll
  for (int mt = 0; mt < 2; mt++) {
    float inv[4];
#pragma unroll
    for (int r = 0; r < 4; r++) inv[r] = 1.0f / lp[mt][r];
#pragma unroll
    for (int nt = 0; nt < 4; nt++)
#pragma unroll
      for (int r = 0; r < 4; r++) {
        int srow = q0 + w * 32 + mt * 16 + quad * 4 + r;
        int col = h * 64 + nt * 16 + l16;
        size_t off = (size_t)(b * 2048 + srow) * 2048 + col;
        float g = bf2f(gate[off]);
        float sig = 1.0f / (1.0f + __builtin_amdgcn_exp2f(-g * LOG2E));
        act[off] = f2bf(O[mt][nt][r] * inv[r] * sig);
      }
  }
}

// ------------------------------------------------------------------ launcher
extern "C" void kernel_launch(void* const* d_in, const int* in_sizes, int n_in,
                              void* d_out, int out_size, void* d_ws, size_t ws_size,
                              hipStream_t stream) {
  const float* hid  = (const float*)d_in[0];
  const float* cosb = (const float*)d_in[1];
  const float* sinb = (const float*)d_in[2];
  const float* Wq   = (const float*)d_in[3];
  const float* Wk   = (const float*)d_in[4];
  const float* Wv   = (const float*)d_in[5];
  const float* Wg   = (const float*)d_in[6];
  const float* Wo   = (const float*)d_in[7];
  const float* qg   = (const float*)d_in[8];
  const float* kg   = (const float*)d_in[9];
  float* out = (float*)d_out;

  char* ws = (char*)d_ws;
  unsigned short* Xb   = (unsigned short*)(ws);              // 16,777,216 B
  unsigned short* WqB  = (unsigned short*)(ws + 16777216);   //  8,388,608
  unsigned short* WkB  = (unsigned short*)(ws + 25165824);   //  1,048,576
  unsigned short* WvB  = (unsigned short*)(ws + 26214400);   //  1,048,576
  unsigned short* WgB  = (unsigned short*)(ws + 27262976);   //  8,388,608
  unsigned short* WoB  = (unsigned short*)(ws + 35651584);   //  8,388,608
  unsigned short* Qraw = (unsigned short*)(ws + 44040192);   // 16,777,216
  unsigned short* Kraw = (unsigned short*)(ws + 60817408);   //  2,097,152
  unsigned short* Vraw = (unsigned short*)(ws + 62914560);   //  2,097,152
  unsigned short* gate = (unsigned short*)(ws + 65011712);   // 16,777,216
  unsigned short* Kn   = (unsigned short*)(ws + 81788928);   //  2,097,152
  unsigned short* Vt   = (unsigned short*)(ws + 83886080);   //  2,097,152
  // region reuse (strictly ordered by stream):
  unsigned short* Qn  = Xb;    // Xb dead after gemm_qkvg
  unsigned short* act = WqB;   // Wq..Wg bf16 dead after gemm_qkvg

  // f32 -> bf16
  {
    struct { const float* s; unsigned short* d; int n; } jobs[6] = {
      {hid, Xb, 8388608}, {Wq, WqB, 4194304}, {Wk, WkB, 524288},
      {Wv, WvB, 524288}, {Wg, WgB, 4194304}, {Wo, WoB, 4194304}};
    for (int i = 0; i < 6; i++) {
      int n4 = jobs[i].n / 4;
      cvt_f32_bf16<<<dim3((n4 + 255) / 256), dim3(256), 0, stream>>>(
          jobs[i].s, jobs[i].d, n4);
    }
  }

  gemm_qkvg<<<dim3(32, 36), dim3(256), 0, stream>>>(
      Xb, WqB, WkB, WvB, WgB, Qraw, Kraw, Vraw, gate);

  prep_qkv<<<dim3(40960), dim3(256), 0, stream>>>(
      Qraw, Kraw, Vraw, cosb, sinb, qg, kg, Qn, Kn, Vt);

  attn<<<dim3(16, 64), dim3(256), 0, stream>>>(Qn, Kn, Vt, gate, act);

  gemm_out_k<<<dim3(32, 16), dim3(256), 0, stream>>>(act, WoB, out);
}

// Round 4
// 430.131 us; speedup vs baseline: 1.6844x; 1.6844x over previous
//
#include <hip/hip_runtime.h>

// AfmoeAttention on MI355X (gfx950), round 4.
// r3 post-mortem: direct global->VGPR frag loads caused ~284MB of scratch
// spill traffic (WRITE_SIZE counter) — reverted to r2's async16-staged,
// XOR-swizzled structure. Kept r3's validated static-max softmax (|s|<=8
// provable from RMSNorm) -> no max tracking, no rescale, epilogue-only l
// reduction. kv processed in 64-halves (sc[2][4], lower reg pressure),
// Ps in its own region: 48 KB LDS, launch_bounds(256,3).

#define LOG2E 1.44269504088896340736f

typedef __attribute__((ext_vector_type(4))) float f32x4;
typedef __attribute__((ext_vector_type(8))) short bf16x8;   // 8 x bf16 (4 VGPRs)

__device__ __forceinline__ float bf2f(unsigned short u) {
  union { unsigned u; float f; } x; x.u = ((unsigned)u) << 16; return x.f;
}
__device__ __forceinline__ unsigned short f2bf(float f) {
  union { float f; unsigned u; } x; x.f = f;
  unsigned r = x.u + 0x7fffu + ((x.u >> 16) & 1u);   // RNE
  return (unsigned short)(r >> 16);
}

// async global->LDS, 16B per lane. LDS dest = wave-uniform base + lane*16.
__device__ __forceinline__ void async16(void* lds, const void* g) {
  __builtin_amdgcn_global_load_lds(
      (const __attribute__((address_space(1))) unsigned*)g,
      (__attribute__((address_space(3))) unsigned*)lds, 16, 0, 0);
}
__device__ __forceinline__ void lds_fence() {
  __asm__ volatile("s_waitcnt lgkmcnt(0)" ::: "memory");
}

// ---------------------------------------------------------------- cvt kernel
__global__ __launch_bounds__(256) void cvt_f32_bf16(
    const float* __restrict__ src, unsigned short* __restrict__ dst, int n4) {
  int i = blockIdx.x * 256 + threadIdx.x;
  if (i >= n4) return;
  float4 v = reinterpret_cast<const float4*>(src)[i];
  ushort4 u;
  u.x = f2bf(v.x); u.y = f2bf(v.y); u.z = f2bf(v.z); u.w = f2bf(v.w);
  reinterpret_cast<ushort4*>(dst)[i] = u;
}

// ------------------------------------------------------------- GEMM template
// C[M,N] = A[M,K] @ W[N,K]^T, 128x128 tile, BK=32, 4 waves each 64x64.
template <typename CT>
__device__ __forceinline__ void gemm128(
    const unsigned short* __restrict__ A, const unsigned short* __restrict__ W,
    CT* __restrict__ C, int m0, int n0, int ldc, int K,
    unsigned short* As, unsigned short* Bs) {
  const int tid = threadIdx.x;
  const int w = tid >> 6, l = tid & 63, quad = l >> 4, l16 = l & 15;
  const int wm = (w & 1) * 64, wn = (w >> 1) * 64;

  f32x4 acc[4][4];
  const f32x4 Z4 = {0.f, 0.f, 0.f, 0.f};
#pragma unroll
  for (int i = 0; i < 4; i++)
#pragma unroll
    for (int j = 0; j < 4; j++) acc[i][j] = Z4;

  const int srow = tid >> 2;            // 0..63
  const int scol = (tid & 3) * 8;       // elem offset in K
  const unsigned short* gA = A + (size_t)(m0 + srow) * K + scol;
  const unsigned short* gB = W + (size_t)(n0 + srow) * K + scol;
  unsigned short* lA = As + tid * 8;    // byte offset tid*16
  unsigned short* lB = Bs + tid * 8;

  for (int kb = 0; kb < K; kb += 32) {
    async16(lA,        gA + kb);
    async16(lA + 2048, gA + (size_t)64 * K + kb);
    async16(lB,        gB + kb);
    async16(lB + 2048, gB + (size_t)64 * K + kb);
    __syncthreads();   // waits vmcnt(0): async LDS writes landed

    bf16x8 af[4], bf[4];
#pragma unroll
    for (int mt = 0; mt < 4; mt++)
      af[mt] = *(const bf16x8*)&As[(wm + mt * 16 + l16) * 32 + quad * 8];
#pragma unroll
    for (int nt = 0; nt < 4; nt++)
      bf[nt] = *(const bf16x8*)&Bs[(wn + nt * 16 + l16) * 32 + quad * 8];
#pragma unroll
    for (int mt = 0; mt < 4; mt++)
#pragma unroll
      for (int nt = 0; nt < 4; nt++)
        acc[mt][nt] = __builtin_amdgcn_mfma_f32_16x16x32_bf16(
            af[mt], bf[nt], acc[mt][nt], 0, 0, 0);
    __syncthreads();   // all reads done before next tile's staging
  }

  // C/D layout: col = lane&15, row = quad*4 + reg
#pragma unroll
  for (int mt = 0; mt < 4; mt++)
#pragma unroll
    for (int nt = 0; nt < 4; nt++) {
      int row = m0 + wm + mt * 16 + quad * 4;
      int col = n0 + wn + nt * 16 + l16;
#pragma unroll
      for (int r = 0; r < 4; r++) {
        if constexpr (sizeof(CT) == 2)
          C[(size_t)(row + r) * ldc + col] = f2bf(acc[mt][nt][r]);
        else
          C[(size_t)(row + r) * ldc + col] = acc[mt][nt][r];
      }
    }
}

__global__ __launch_bounds__(256) void gemm_qkvg(
    const unsigned short* __restrict__ X,
    const unsigned short* __restrict__ Wq, const unsigned short* __restrict__ Wk,
    const unsigned short* __restrict__ Wv, const unsigned short* __restrict__ Wg,
    unsigned short* __restrict__ Qr, unsigned short* __restrict__ Kr,
    unsigned short* __restrict__ Vr, unsigned short* __restrict__ Gr) {
  __shared__ __attribute__((aligned(16))) unsigned short As[128 * 32];
  __shared__ __attribute__((aligned(16))) unsigned short Bs[128 * 32];
  int ny = blockIdx.y;
  const unsigned short* W; unsigned short* C; int n0, ldc;
  if (ny < 16)      { W = Wq; C = Qr; n0 = ny * 128;        ldc = 2048; }
  else if (ny < 18) { W = Wk; C = Kr; n0 = (ny - 16) * 128; ldc = 256;  }
  else if (ny < 20) { W = Wv; C = Vr; n0 = (ny - 18) * 128; ldc = 256;  }
  else              { W = Wg; C = Gr; n0 = (ny - 20) * 128; ldc = 2048; }
  gemm128<unsigned short>(X, W, C, blockIdx.x * 128, n0, ldc, 2048, As, Bs);
}

__global__ __launch_bounds__(256) void gemm_out_k(
    const unsigned short* __restrict__ A, const unsigned short* __restrict__ W,
    float* __restrict__ C) {
  __shared__ __attribute__((aligned(16))) unsigned short As[128 * 32];
  __shared__ __attribute__((aligned(16))) unsigned short Bs[128 * 32];
  gemm128<float>(A, W, C, blockIdx.x * 128, blockIdx.y * 128, 2048, 2048, As, Bs);
}

// ------------------------------------------------------ RMSNorm+RoPE+transpose
__global__ __launch_bounds__(256) void prep_qkv(
    const unsigned short* __restrict__ Qr, const unsigned short* __restrict__ Kr,
    const unsigned short* __restrict__ Vr,
    const float* __restrict__ cosb, const float* __restrict__ sinb,
    const float* __restrict__ qg, const float* __restrict__ kg,
    unsigned short* __restrict__ Qn, unsigned short* __restrict__ Kn,
    unsigned short* __restrict__ Vt) {
  int idx = blockIdx.x * 4 + (threadIdx.x >> 6);   // global unit index
  int d = threadIdx.x & 63;
  int token = idx / 40;
  int unit = idx - token * 40;
  int b = token >> 11, s = token & 2047;

  if (unit >= 36) {   // V transpose (scattered 2B stores, small total)
    int kvh = unit - 36;
    Vt[((size_t)(b * 4 + kvh) * 64 + d) * 2048 + s] =
        Vr[(size_t)token * 256 + kvh * 64 + d];
    return;
  }
  const unsigned short* src; const float* gamma; float scale; unsigned short* dst;
  if (unit < 32) {
    src = Qr + (size_t)token * 2048 + unit * 64;
    gamma = qg; scale = 0.125f;               // 1/sqrt(D)
    dst = Qn + ((size_t)(b * 32 + unit) * 2048 + s) * 64;
  } else {
    int kvh = unit - 32;
    src = Kr + (size_t)token * 256 + kvh * 64;
    gamma = kg; scale = 1.0f;
    dst = Kn + ((size_t)(b * 4 + kvh) * 2048 + s) * 64;
  }
  float x = bf2f(src[d]);
  float ss = x * x;
#pragma unroll
  for (int off = 32; off >= 1; off >>= 1) ss += __shfl_xor(ss, off);
  float rr = rsqrtf(ss * (1.0f / 64.0f) + 1e-6f);
  float xn = x * rr * gamma[d];
  float other = __shfl_xor(xn, 32);           // partner at d^32
  float rot = (d < 32) ? -other : other;      // rotate_half
  size_t cs = (size_t)(b * 2048 + s) * 64 + d;
  dst[d] = f2bf((xn * cosb[cs] + rot * sinb[cs]) * scale);
}

// ---------------------------------------------------------- flash attention
// grid: (S/128, B*NH). 4 waves, each owns 32 Q rows. KV tiles of 128,
// processed as two kv-64 halves. Static-max softmax (no max tracking).
// LDS 48 KB: Ks[128][64] sw (hosts Qs in prologue), Vts[64][128] sw,
// Ps 4 x [32][64] sw wave-private. Swizzles as r2 (verified 0 conflicts).
__global__ __launch_bounds__(256, 3) void attn(
    const unsigned short* __restrict__ Qn, const unsigned short* __restrict__ Kn,
    const unsigned short* __restrict__ Vt, const unsigned short* __restrict__ gate,
    unsigned short* __restrict__ act) {
  __shared__ __attribute__((aligned(16))) unsigned short smem[24576];  // 48 KB
  unsigned short* Ks  = smem;           // [128][64] sw; Qs in prologue
  unsigned short* Vts = smem + 8192;    // [64][128] sw
  unsigned short* Ps  = smem + 16384;   // 4 x [32 q][64 kv] sw

  const int tid = threadIdx.x, w = tid >> 6, l = tid & 63;
  const int quad = l >> 4, l16 = l & 15, l7 = l16 & 7;
  const int bh = blockIdx.y, b = bh >> 5, h = bh & 31, kvh = h >> 3;
  const int q0 = blockIdx.x * 128;

  const unsigned short* Qg = Qn + ((size_t)(b * 32 + h) * 2048 + q0) * 64;
  const unsigned short* Kg = Kn + (size_t)(b * 4 + kvh) * 2048 * 64;
  const unsigned short* Vg = Vt + (size_t)(b * 4 + kvh) * 64 * 2048;
  unsigned short* Pw = Ps + w * 2048;   // wave-private [32 q][64 kv], swizzled

  // swizzled staging source chunk indices
  const int kq_src = ((tid & 7) ^ ((tid >> 3) & 7)) * 8;   // K/Q staging
  const int v_src  = (((tid & 15) ^ (tid >> 4)) & 15) * 8; // V staging

  // ---- prologue: stage Q (swizzled) into Ks region, read q-fragments
#pragma unroll
  for (int i = 0; i < 4; i++)
    async16(Ks + i * 2048 + tid * 8,
            Qg + (size_t)(i * 32 + (tid >> 3)) * 64 + kq_src);
  __syncthreads();
  bf16x8 qf[2][2];
#pragma unroll
  for (int mt = 0; mt < 2; mt++)
#pragma unroll
    for (int ks = 0; ks < 2; ks++) {
      int row = w * 32 + mt * 16 + l16;           // row&7 == l7
      qf[mt][ks] = *(const bf16x8*)&Ks[row * 64 + ((ks * 4 + quad) ^ l7) * 8];
    }
  __syncthreads();   // Qs region free for K staging

  const f32x4 Z4 = {0.f, 0.f, 0.f, 0.f};
  f32x4 O[2][4];
  float lp[2][4];
#pragma unroll
  for (int mt = 0; mt < 2; mt++) {
#pragma unroll
    for (int nt = 0; nt < 4; nt++) O[mt][nt] = Z4;
#pragma unroll
    for (int r = 0; r < 4; r++) lp[mt][r] = 0.f;
  }

  for (int kt = 0; kt < 16; kt++) {
    const int s0 = kt * 128;
#pragma unroll
    for (int i = 0; i < 4; i++)
      async16(Ks + i * 2048 + tid * 8,
              Kg + (size_t)(s0 + i * 32 + (tid >> 3)) * 64 + kq_src);
#pragma unroll
    for (int i = 0; i < 4; i++)
      async16(Vts + i * 2048 + tid * 8,
              Vg + (size_t)(i * 16 + (tid >> 4)) * 2048 + s0 + v_src);
    __syncthreads();

#pragma unroll
    for (int half = 0; half < 2; half++) {
      // ---- S = Q K^T over this kv-64 half
      f32x4 sc[2][4];
#pragma unroll
      for (int mt = 0; mt < 2; mt++)
#pragma unroll
        for (int nt = 0; nt < 4; nt++) sc[mt][nt] = Z4;
#pragma unroll
      for (int nt = 0; nt < 4; nt++) {
        int row = half * 64 + nt * 16 + l16;      // row&7 == l7
        bf16x8 kf0 = *(const bf16x8*)&Ks[row * 64 + (quad ^ l7) * 8];
        bf16x8 kf1 = *(const bf16x8*)&Ks[row * 64 + ((4 + quad) ^ l7) * 8];
#pragma unroll
        for (int mt = 0; mt < 2; mt++) {
          sc[mt][nt] = __builtin_amdgcn_mfma_f32_16x16x32_bf16(qf[mt][0], kf0, sc[mt][nt], 0, 0, 0);
          sc[mt][nt] = __builtin_amdgcn_mfma_f32_16x16x32_bf16(qf[mt][1], kf1, sc[mt][nt], 0, 0, 0);
        }
      }

      // ---- p = exp(s) (static max), truncate to bf16; l summed from the
      // SAME truncated values. Store P swizzled to wave-private LDS.
#pragma unroll
      for (int mt = 0; mt < 2; mt++)
#pragma unroll
        for (int nt = 0; nt < 4; nt++)
#pragma unroll
          for (int r = 0; r < 4; r++) {
            float p = __builtin_amdgcn_exp2f(sc[mt][nt][r] * LOG2E);
            union { float f; unsigned u; } x; x.f = p;
            union { unsigned u; float f; } t; t.u = x.u & 0xffff0000u;
            lp[mt][r] += t.f;
            int q = mt * 16 + quad * 4 + r;
            int chunk = nt * 2 + (l16 >> 3);
            Pw[q * 64 + (chunk ^ (q & 7)) * 8 + l7] = (unsigned short)(x.u >> 16);
          }
      lds_fence();   // P writes visible before reads (same wave)

      // ---- O += P V
#pragma unroll
      for (int ks2 = 0; ks2 < 2; ks2++) {
        bf16x8 pf[2];
#pragma unroll
        for (int mt = 0; mt < 2; mt++) {
          int q = mt * 16 + l16;                  // q&7 == l7
          pf[mt] = *(const bf16x8*)&Pw[q * 64 + (((ks2 * 4 + quad) ^ l7)) * 8];
        }
#pragma unroll
        for (int nt2 = 0; nt2 < 4; nt2++) {
          int vrow = nt2 * 16 + l16;              // vrow&15 == l16
          int vchunk = half * 8 + ks2 * 4 + quad;
          bf16x8 vf = *(const bf16x8*)&Vts[vrow * 128 + (vchunk ^ l16) * 8];
#pragma unroll
          for (int mt = 0; mt < 2; mt++)
            O[mt][nt2] = __builtin_amdgcn_mfma_f32_16x16x32_bf16(
                pf[mt], vf, O[mt][nt2], 0, 0, 0);
        }
      }
      lds_fence();   // this half's P reads retired before next half's writes
    }
    __syncthreads();   // Ks/Vts free for next tile's staging
  }

  // ---- final l reduction across the 16-lane column groups (once)
#pragma unroll
  for (int mt = 0; mt < 2; mt++)
#pragma unroll
    for (int r = 0; r < 4; r++) {
      float s = lp[mt][r];
#pragma unroll
      for (int off = 1; off < 16; off <<= 1) s += __shfl_xor(s, off);
      lp[mt][r] = s;
    }

  // ---- epilogue: O/l * sigmoid(gate) -> act[b][s][h*64+d]
#pragma unroll
  for (int mt = 0; mt < 2; mt++) {
    float inv[4];
#pragma unroll
    for (int r = 0; r < 4; r++) inv[r] = 1.0f / lp[mt][r];
#pragma unroll
    for (int nt = 0; nt < 4; nt++)
#pragma unroll
      for (int r = 0; r < 4; r++) {
        int srow = q0 + w * 32 + mt * 16 + quad * 4 + r;
        int col = h * 64 + nt * 16 + l16;
        size_t off = (size_t)(b * 2048 + srow) * 2048 + col;
        float g = bf2f(gate[off]);
        float sig = 1.0f / (1.0f + __builtin_amdgcn_exp2f(-g * LOG2E));
        act[off] = f2bf(O[mt][nt][r] * inv[r] * sig);
      }
  }
}

// ------------------------------------------------------------------ launcher
extern "C" void kernel_launch(void* const* d_in, const int* in_sizes, int n_in,
                              void* d_out, int out_size, void* d_ws, size_t ws_size,
                              hipStream_t stream) {
  const float* hid  = (const float*)d_in[0];
  const float* cosb = (const float*)d_in[1];
  const float* sinb = (const float*)d_in[2];
  const float* Wq   = (const float*)d_in[3];
  const float* Wk   = (const float*)d_in[4];
  const float* Wv   = (const float*)d_in[5];
  const float* Wg   = (const float*)d_in[6];
  const float* Wo   = (const float*)d_in[7];
  const float* qg   = (const float*)d_in[8];
  const float* kg   = (const float*)d_in[9];
  float* out = (float*)d_out;

  char* ws = (char*)d_ws;
  unsigned short* Xb   = (unsigned short*)(ws);              // 16,777,216 B
  unsigned short* WqB  = (unsigned short*)(ws + 16777216);   //  8,388,608
  unsigned short* WkB  = (unsigned short*)(ws + 25165824);   //  1,048,576
  unsigned short* WvB  = (unsigned short*)(ws + 26214400);   //  1,048,576
  unsigned short* WgB  = (unsigned short*)(ws + 27262976);   //  8,388,608
  unsigned short* WoB  = (unsigned short*)(ws + 35651584);   //  8,388,608
  unsigned short* Qraw = (unsigned short*)(ws + 44040192);   // 16,777,216
  unsigned short* Kraw = (unsigned short*)(ws + 60817408);   //  2,097,152
  unsigned short* Vraw = (unsigned short*)(ws + 62914560);   //  2,097,152
  unsigned short* gate = (unsigned short*)(ws + 65011712);   // 16,777,216
  unsigned short* Kn   = (unsigned short*)(ws + 81788928);   //  2,097,152
  unsigned short* Vt   = (unsigned short*)(ws + 83886080);   //  2,097,152
  // region reuse (strictly ordered by stream):
  unsigned short* Qn  = Xb;    // Xb dead after gemm_qkvg
  unsigned short* act = WqB;   // Wq..Wg bf16 dead after gemm_qkvg

  // f32 -> bf16
  {
    struct { const float* s; unsigned short* d; int n; } jobs[6] = {
      {hid, Xb, 8388608}, {Wq, WqB, 4194304}, {Wk, WkB, 524288},
      {Wv, WvB, 524288}, {Wg, WgB, 4194304}, {Wo, WoB, 4194304}};
    for (int i = 0; i < 6; i++) {
      int n4 = jobs[i].n / 4;
      cvt_f32_bf16<<<dim3((n4 + 255) / 256), dim3(256), 0, stream>>>(
          jobs[i].s, jobs[i].d, n4);
    }
  }

  gemm_qkvg<<<dim3(32, 36), dim3(256), 0, stream>>>(
      Xb, WqB, WkB, WvB, WgB, Qraw, Kraw, Vraw, gate);

  prep_qkv<<<dim3(40960), dim3(256), 0, stream>>>(
      Qraw, Kraw, Vraw, cosb, sinb, qg, kg, Qn, Kn, Vt);

  attn<<<dim3(16, 64), dim3(256), 0, stream>>>(Qn, Kn, Vt, gate, act);

  gemm_out_k<<<dim3(32, 16), dim3(256), 0, stream>>>(act, WoB, out);
}

// Round 5
// 411.341 us; speedup vs baseline: 1.7614x; 1.0457x over previous
//
#include <hip/hip_runtime.h>

// AfmoeAttention on MI355X (gfx950), round 5.
// vs r4: (a) attention K-loop restructured to pipelined double-buffered
// staging with ONE __syncthreads per kv-64 tile (stage(t+1) overlaps
// compute(t)); (b) LDS 40 KB -> 4 blocks/CU, grid exactly resident (no
// tail); (c) LOG2E folded into K (prep), exp2 direct; (d) 6 cvt launches
// fused into 1. GEMMs unchanged.

#define LOG2E 1.44269504088896340736f

typedef __attribute__((ext_vector_type(4))) float f32x4;
typedef __attribute__((ext_vector_type(8))) short bf16x8;   // 8 x bf16 (4 VGPRs)

__device__ __forceinline__ float bf2f(unsigned short u) {
  union { unsigned u; float f; } x; x.u = ((unsigned)u) << 16; return x.f;
}
__device__ __forceinline__ unsigned short f2bf(float f) {
  union { float f; unsigned u; } x; x.f = f;
  unsigned r = x.u + 0x7fffu + ((x.u >> 16) & 1u);   // RNE
  return (unsigned short)(r >> 16);
}

// async global->LDS, 16B per lane. LDS dest = wave-uniform base + lane*16.
__device__ __forceinline__ void async16(void* lds, const void* g) {
  __builtin_amdgcn_global_load_lds(
      (const __attribute__((address_space(1))) unsigned*)g,
      (__attribute__((address_space(3))) unsigned*)lds, 16, 0, 0);
}
__device__ __forceinline__ void lds_fence() {
  __asm__ volatile("s_waitcnt lgkmcnt(0)" ::: "memory");
}

// ---------------------------------------------------------- fused cvt kernel
// f4-index prefix: hid 2097152 | Wq 1048576 | Wk 131072 | Wv 131072 |
// Wg 1048576 | Wo 1048576  (total 5505024; all boundaries block-aligned)
__global__ __launch_bounds__(256) void cvt_all(
    const float* __restrict__ s0, const float* __restrict__ s1,
    const float* __restrict__ s2, const float* __restrict__ s3,
    const float* __restrict__ s4, const float* __restrict__ s5,
    unsigned short* __restrict__ d0, unsigned short* __restrict__ d1,
    unsigned short* __restrict__ d2, unsigned short* __restrict__ d3,
    unsigned short* __restrict__ d4, unsigned short* __restrict__ d5) {
  long i = (long)blockIdx.x * 256 + threadIdx.x;   // f4 index
  const float* s; unsigned short* d; long off;
  if      (i < 2097152) { s = s0; d = d0; off = 0; }
  else if (i < 3145728) { s = s1; d = d1; off = 2097152; }
  else if (i < 3276800) { s = s2; d = d2; off = 3145728; }
  else if (i < 3407872) { s = s3; d = d3; off = 3276800; }
  else if (i < 4456448) { s = s4; d = d4; off = 3407872; }
  else                  { s = s5; d = d5; off = 4456448; }
  long j = i - off;
  float4 v = reinterpret_cast<const float4*>(s)[j];
  ushort4 u;
  u.x = f2bf(v.x); u.y = f2bf(v.y); u.z = f2bf(v.z); u.w = f2bf(v.w);
  reinterpret_cast<ushort4*>(d)[j] = u;
}

// ------------------------------------------------------------- GEMM template
// C[M,N] = A[M,K] @ W[N,K]^T, 128x128 tile, BK=32, 4 waves each 64x64.
template <typename CT>
__device__ __forceinline__ void gemm128(
    const unsigned short* __restrict__ A, const unsigned short* __restrict__ W,
    CT* __restrict__ C, int m0, int n0, int ldc, int K,
    unsigned short* As, unsigned short* Bs) {
  const int tid = threadIdx.x;
  const int w = tid >> 6, l = tid & 63, quad = l >> 4, l16 = l & 15;
  const int wm = (w & 1) * 64, wn = (w >> 1) * 64;

  f32x4 acc[4][4];
  const f32x4 Z4 = {0.f, 0.f, 0.f, 0.f};
#pragma unroll
  for (int i = 0; i < 4; i++)
#pragma unroll
    for (int j = 0; j < 4; j++) acc[i][j] = Z4;

  const int srow = tid >> 2;            // 0..63
  const int scol = (tid & 3) * 8;       // elem offset in K
  const unsigned short* gA = A + (size_t)(m0 + srow) * K + scol;
  const unsigned short* gB = W + (size_t)(n0 + srow) * K + scol;
  unsigned short* lA = As + tid * 8;    // byte offset tid*16
  unsigned short* lB = Bs + tid * 8;

  for (int kb = 0; kb < K; kb += 32) {
    async16(lA,        gA + kb);
    async16(lA + 2048, gA + (size_t)64 * K + kb);
    async16(lB,        gB + kb);
    async16(lB + 2048, gB + (size_t)64 * K + kb);
    __syncthreads();   // waits vmcnt(0): async LDS writes landed

    bf16x8 af[4], bf[4];
#pragma unroll
    for (int mt = 0; mt < 4; mt++)
      af[mt] = *(const bf16x8*)&As[(wm + mt * 16 + l16) * 32 + quad * 8];
#pragma unroll
    for (int nt = 0; nt < 4; nt++)
      bf[nt] = *(const bf16x8*)&Bs[(wn + nt * 16 + l16) * 32 + quad * 8];
#pragma unroll
    for (int mt = 0; mt < 4; mt++)
#pragma unroll
      for (int nt = 0; nt < 4; nt++)
        acc[mt][nt] = __builtin_amdgcn_mfma_f32_16x16x32_bf16(
            af[mt], bf[nt], acc[mt][nt], 0, 0, 0);
    __syncthreads();   // all reads done before next tile's staging
  }

  // C/D layout: col = lane&15, row = quad*4 + reg
#pragma unroll
  for (int mt = 0; mt < 4; mt++)
#pragma unroll
    for (int nt = 0; nt < 4; nt++) {
      int row = m0 + wm + mt * 16 + quad * 4;
      int col = n0 + wn + nt * 16 + l16;
#pragma unroll
      for (int r = 0; r < 4; r++) {
        if constexpr (sizeof(CT) == 2)
          C[(size_t)(row + r) * ldc + col] = f2bf(acc[mt][nt][r]);
        else
          C[(size_t)(row + r) * ldc + col] = acc[mt][nt][r];
      }
    }
}

__global__ __launch_bounds__(256) void gemm_qkvg(
    const unsigned short* __restrict__ X,
    const unsigned short* __restrict__ Wq, const unsigned short* __restrict__ Wk,
    const unsigned short* __restrict__ Wv, const unsigned short* __restrict__ Wg,
    unsigned short* __restrict__ Qr, unsigned short* __restrict__ Kr,
    unsigned short* __restrict__ Vr, unsigned short* __restrict__ Gr) {
  __shared__ __attribute__((aligned(16))) unsigned short As[128 * 32];
  __shared__ __attribute__((aligned(16))) unsigned short Bs[128 * 32];
  int ny = blockIdx.y;
  const unsigned short* W; unsigned short* C; int n0, ldc;
  if (ny < 16)      { W = Wq; C = Qr; n0 = ny * 128;        ldc = 2048; }
  else if (ny < 18) { W = Wk; C = Kr; n0 = (ny - 16) * 128; ldc = 256;  }
  else if (ny < 20) { W = Wv; C = Vr; n0 = (ny - 18) * 128; ldc = 256;  }
  else              { W = Wg; C = Gr; n0 = (ny - 20) * 128; ldc = 2048; }
  gemm128<unsigned short>(X, W, C, blockIdx.x * 128, n0, ldc, 2048, As, Bs);
}

__global__ __launch_bounds__(256) void gemm_out_k(
    const unsigned short* __restrict__ A, const unsigned short* __restrict__ W,
    float* __restrict__ C) {
  __shared__ __attribute__((aligned(16))) unsigned short As[128 * 32];
  __shared__ __attribute__((aligned(16))) unsigned short Bs[128 * 32];
  gemm128<float>(A, W, C, blockIdx.x * 128, blockIdx.y * 128, 2048, 2048, As, Bs);
}

// ------------------------------------------------------ RMSNorm+RoPE+transpose
// Q scaled by 1/8 (1/sqrt(D)); K scaled by LOG2E so attn can use exp2(s).
__global__ __launch_bounds__(256) void prep_qkv(
    const unsigned short* __restrict__ Qr, const unsigned short* __restrict__ Kr,
    const unsigned short* __restrict__ Vr,
    const float* __restrict__ cosb, const float* __restrict__ sinb,
    const float* __restrict__ qg, const float* __restrict__ kg,
    unsigned short* __restrict__ Qn, unsigned short* __restrict__ Kn,
    unsigned short* __restrict__ Vt) {
  int idx = blockIdx.x * 4 + (threadIdx.x >> 6);   // global unit index
  int d = threadIdx.x & 63;
  int token = idx / 40;
  int unit = idx - token * 40;
  int b = token >> 11, s = token & 2047;

  if (unit >= 36) {   // V transpose (scattered 2B stores, small total)
    int kvh = unit - 36;
    Vt[((size_t)(b * 4 + kvh) * 64 + d) * 2048 + s] =
        Vr[(size_t)token * 256 + kvh * 64 + d];
    return;
  }
  const unsigned short* src; const float* gamma; float scale; unsigned short* dst;
  if (unit < 32) {
    src = Qr + (size_t)token * 2048 + unit * 64;
    gamma = qg; scale = 0.125f;               // 1/sqrt(D)
    dst = Qn + ((size_t)(b * 32 + unit) * 2048 + s) * 64;
  } else {
    int kvh = unit - 32;
    src = Kr + (size_t)token * 256 + kvh * 64;
    gamma = kg; scale = LOG2E;                // fold log2(e) into K
    dst = Kn + ((size_t)(b * 4 + kvh) * 2048 + s) * 64;
  }
  float x = bf2f(src[d]);
  float ss = x * x;
#pragma unroll
  for (int off = 32; off >= 1; off >>= 1) ss += __shfl_xor(ss, off);
  float rr = rsqrtf(ss * (1.0f / 64.0f) + 1e-6f);
  float xn = x * rr * gamma[d];
  float other = __shfl_xor(xn, 32);           // partner at d^32
  float rot = (d < 32) ? -other : other;      // rotate_half
  size_t cs = (size_t)(b * 2048 + s) * 64 + d;
  dst[d] = f2bf((xn * cosb[cs] + rot * sinb[cs]) * scale);
}

// ---------------------------------------------------------- flash attention
// grid: (S/128, B*NH) = 1024 blocks; 4 blocks/CU -> fully resident.
// kv-tile = 64, double-buffered, ONE __syncthreads per tile:
//   loop t: { sync; stage(t+1)->buf[(t+1)&1]; compute(t) on buf[t&1]; }
// (barrier at top of t guarantees compute(t-1) done before stage(t+1)
// overwrites its buffer; the vmcnt(0) drain lands after a full compute.)
// Static-max softmax (|s| bounded via RMSNorm), K pre-scaled by LOG2E.
// LDS 40 KB: buf0 {Ks0 8K, Vts0 8K}, buf1 {Ks1, Vts1}, Ps 8K
// (per-wave [32q][32kv] sub-chunks, phys_chunk = c ^ ((q>>1)&3)).
__global__ __launch_bounds__(256, 4) void attn(
    const unsigned short* __restrict__ Qn, const unsigned short* __restrict__ Kn,
    const unsigned short* __restrict__ Vt, const unsigned short* __restrict__ gate,
    unsigned short* __restrict__ act) {
  __shared__ __attribute__((aligned(16))) unsigned short smem[20480];  // 40 KB
  // buf b: Ks = smem + b*8192, Vts = smem + b*8192 + 4096 (ushorts)
  unsigned short* Ps = smem + 16384;    // 4 x [32 q][32 kv] = 8 KB

  const int tid = threadIdx.x, w = tid >> 6, l = tid & 63;
  const int quad = l >> 4, l16 = l & 15, l7 = l16 & 7;
  const int bh = blockIdx.y, b = bh >> 5, h = bh & 31, kvh = h >> 3;
  const int q0 = blockIdx.x * 128;

  const unsigned short* Qg = Qn + ((size_t)(b * 32 + h) * 2048 + q0) * 64;
  const unsigned short* Kg = Kn + (size_t)(b * 4 + kvh) * 2048 * 64;
  const unsigned short* Vg = Vt + (size_t)(b * 4 + kvh) * 64 * 2048;
  unsigned short* Pw = Ps + w * 1024;   // wave-private [32 q][32 kv]

  // swizzled staging source chunk (8 chunks/row, phys = c ^ (row&7))
  const int kq_src = ((tid & 7) ^ ((tid >> 3) & 7)) * 8;

  // ---- prologue: stage Q [128][64] into smem[0..8192), read q-fragments
#pragma unroll
  for (int i = 0; i < 4; i++)
    async16(smem + i * 2048 + tid * 8,
            Qg + (size_t)(i * 32 + (tid >> 3)) * 64 + kq_src);
  __syncthreads();
  bf16x8 qf[2][2];
#pragma unroll
  for (int mt = 0; mt < 2; mt++)
#pragma unroll
    for (int ks = 0; ks < 2; ks++) {
      int row = w * 32 + mt * 16 + l16;           // row&7 == l7
      qf[mt][ks] = *(const bf16x8*)&smem[row * 64 + ((ks * 4 + quad) ^ l7) * 8];
    }
  __syncthreads();   // Q region free for K/V staging

  const f32x4 Z4 = {0.f, 0.f, 0.f, 0.f};
  f32x4 O[2][4];
  float lp[2][4];
#pragma unroll
  for (int mt = 0; mt < 2; mt++) {
#pragma unroll
    for (int nt = 0; nt < 4; nt++) O[mt][nt] = Z4;
#pragma unroll
    for (int r = 0; r < 4; r++) lp[mt][r] = 0.f;
  }

  // stage tile 0 into buf0
#pragma unroll
  for (int i = 0; i < 2; i++) {
    async16(smem + i * 2048 + tid * 8,
            Kg + (size_t)(i * 32 + (tid >> 3)) * 64 + kq_src);
    async16(smem + 4096 + i * 2048 + tid * 8,
            Vg + (size_t)(i * 32 + (tid >> 3)) * 2048 + kq_src);
  }

  for (int kt = 0; kt < 32; kt++) {
    __syncthreads();   // drains stage(kt); all waves past compute(kt-1)

    if (kt < 31) {     // stage tile kt+1 into the other buffer (overlapped)
      unsigned short* nb = smem + ((kt + 1) & 1) * 8192;
      const int s1 = (kt + 1) * 64;
#pragma unroll
      for (int i = 0; i < 2; i++) {
        async16(nb + i * 2048 + tid * 8,
                Kg + (size_t)(s1 + i * 32 + (tid >> 3)) * 64 + kq_src);
        async16(nb + 4096 + i * 2048 + tid * 8,
                Vg + (size_t)(i * 32 + (tid >> 3)) * 2048 + s1 + kq_src);
      }
    }

    unsigned short* Ks  = smem + (kt & 1) * 8192;
    unsigned short* Vts = Ks + 4096;

    // ---- S = Q K^T over this kv-64 tile
    f32x4 sc[2][4];
#pragma unroll
    for (int mt = 0; mt < 2; mt++)
#pragma unroll
      for (int nt = 0; nt < 4; nt++) sc[mt][nt] = Z4;
#pragma unroll
    for (int nt = 0; nt < 4; nt++) {
      int row = nt * 16 + l16;                    // row&7 == l7
      bf16x8 kf0 = *(const bf16x8*)&Ks[row * 64 + (quad ^ l7) * 8];
      bf16x8 kf1 = *(const bf16x8*)&Ks[row * 64 + ((4 + quad) ^ l7) * 8];
#pragma unroll
      for (int mt = 0; mt < 2; mt++) {
        sc[mt][nt] = __builtin_amdgcn_mfma_f32_16x16x32_bf16(qf[mt][0], kf0, sc[mt][nt], 0, 0, 0);
        sc[mt][nt] = __builtin_amdgcn_mfma_f32_16x16x32_bf16(qf[mt][1], kf1, sc[mt][nt], 0, 0, 0);
      }
    }

    // ---- softmax + PV in two kv-32 sub-chunks through wave-private Ps
#pragma unroll
    for (int ks2 = 0; ks2 < 2; ks2++) {
      // p = exp2(s) (K pre-scaled by log2e), truncate to bf16; lp summed
      // from the SAME truncated values (bias cancels in normalization).
#pragma unroll
      for (int mt = 0; mt < 2; mt++)
#pragma unroll
        for (int ntl = 0; ntl < 2; ntl++) {
          int nt = ks2 * 2 + ntl;
#pragma unroll
          for (int r = 0; r < 4; r++) {
            float p = __builtin_amdgcn_exp2f(sc[mt][nt][r]);
            union { float f; unsigned u; } x; x.f = p;
            union { unsigned u; float f; } t; t.u = x.u & 0xffff0000u;
            lp[mt][r] += t.f;
            int q = mt * 16 + quad * 4 + r;
            int c = ntl * 2 + (l16 >> 3);
            int phys = c ^ ((q >> 1) & 3);
            Pw[q * 32 + phys * 8 + l7] = (unsigned short)(x.u >> 16);
          }
        }
      lds_fence();   // P writes visible before reads (same wave)

      bf16x8 pf[2];
#pragma unroll
      for (int mt = 0; mt < 2; mt++) {
        int q = mt * 16 + l16;
        int phys = quad ^ ((l16 >> 1) & 3);
        pf[mt] = *(const bf16x8*)&Pw[q * 32 + phys * 8];
      }
#pragma unroll
      for (int nt2 = 0; nt2 < 4; nt2++) {
        int d = nt2 * 16 + l16;                   // d&7 == l7
        bf16x8 vf = *(const bf16x8*)&Vts[d * 64 + ((ks2 * 4 + quad) ^ l7) * 8];
#pragma unroll
        for (int mt = 0; mt < 2; mt++)
          O[mt][nt2] = __builtin_amdgcn_mfma_f32_16x16x32_bf16(
              pf[mt], vf, O[mt][nt2], 0, 0, 0);
      }
      lds_fence();   // sub-chunk reads retired before next sub-chunk writes
    }
  }

  // ---- final l reduction across the 16-lane column groups (once)
#pragma unroll
  for (int mt = 0; mt < 2; mt++)
#pragma unroll
    for (int r = 0; r < 4; r++) {
      float s = lp[mt][r];
#pragma unroll
      for (int off = 1; off < 16; off <<= 1) s += __shfl_xor(s, off);
      lp[mt][r] = s;
    }

  // ---- epilogue: O/l * sigmoid(gate) -> act[b][s][h*64+d]
#pragma unroll
  for (int mt = 0; mt < 2; mt++) {
    float inv[4];
#pragma unroll
    for (int r = 0; r < 4; r++) inv[r] = 1.0f / lp[mt][r];
#pragma unroll
    for (int nt = 0; nt < 4; nt++)
#pragma unroll
      for (int r = 0; r < 4; r++) {
        int srow = q0 + w * 32 + mt * 16 + quad * 4 + r;
        int col = h * 64 + nt * 16 + l16;
        size_t off = (size_t)(b * 2048 + srow) * 2048 + col;
        float g = bf2f(gate[off]);
        float sig = 1.0f / (1.0f + __builtin_amdgcn_exp2f(-g * LOG2E));
        act[off] = f2bf(O[mt][nt][r] * inv[r] * sig);
      }
  }
}

// ------------------------------------------------------------------ launcher
extern "C" void kernel_launch(void* const* d_in, const int* in_sizes, int n_in,
                              void* d_out, int out_size, void* d_ws, size_t ws_size,
                              hipStream_t stream) {
  const float* hid  = (const float*)d_in[0];
  const float* cosb = (const float*)d_in[1];
  const float* sinb = (const float*)d_in[2];
  const float* Wq   = (const float*)d_in[3];
  const float* Wk   = (const float*)d_in[4];
  const float* Wv   = (const float*)d_in[5];
  const float* Wg   = (const float*)d_in[6];
  const float* Wo   = (const float*)d_in[7];
  const float* qg   = (const float*)d_in[8];
  const float* kg   = (const float*)d_in[9];
  float* out = (float*)d_out;

  char* ws = (char*)d_ws;
  unsigned short* Xb   = (unsigned short*)(ws);              // 16,777,216 B
  unsigned short* WqB  = (unsigned short*)(ws + 16777216);   //  8,388,608
  unsigned short* WkB  = (unsigned short*)(ws + 25165824);   //  1,048,576
  unsigned short* WvB  = (unsigned short*)(ws + 26214400);   //  1,048,576
  unsigned short* WgB  = (unsigned short*)(ws + 27262976);   //  8,388,608
  unsigned short* WoB  = (unsigned short*)(ws + 35651584);   //  8,388,608
  unsigned short* Qraw = (unsigned short*)(ws + 44040192);   // 16,777,216
  unsigned short* Kraw = (unsigned short*)(ws + 60817408);   //  2,097,152
  unsigned short* Vraw = (unsigned short*)(ws + 62914560);   //  2,097,152
  unsigned short* gate = (unsigned short*)(ws + 65011712);   // 16,777,216
  unsigned short* Kn   = (unsigned short*)(ws + 81788928);   //  2,097,152
  unsigned short* Vt   = (unsigned short*)(ws + 83886080);   //  2,097,152
  // region reuse (strictly ordered by stream):
  unsigned short* Qn  = Xb;    // Xb dead after gemm_qkvg
  unsigned short* act = WqB;   // Wq..Wg bf16 dead after gemm_qkvg

  cvt_all<<<dim3(21504), dim3(256), 0, stream>>>(
      hid, Wq, Wk, Wv, Wg, Wo, Xb, WqB, WkB, WvB, WgB, WoB);

  gemm_qkvg<<<dim3(32, 36), dim3(256), 0, stream>>>(
      Xb, WqB, WkB, WvB, WgB, Qraw, Kraw, Vraw, gate);

  prep_qkv<<<dim3(40960), dim3(256), 0, stream>>>(
      Qraw, Kraw, Vraw, cosb, sinb, qg, kg, Qn, Kn, Vt);

  attn<<<dim3(16, 64), dim3(256), 0, stream>>>(Qn, Kn, Vt, gate, act);

  gemm_out_k<<<dim3(32, 16), dim3(256), 0, stream>>>(act, WoB, out);
}

// Round 6
// 392.716 us; speedup vs baseline: 1.8449x; 1.0474x over previous
//
#include <hip/hip_runtime.h>

// AfmoeAttention on MI355X (gfx950), round 6.
// vs r5: (a) XOR-swizzled LDS staging in both GEMMs (kills the 9.4M-cycle
// 8-way fragment-read bank conflict); (b) RMSNorm+RoPE+transposes fused
// into the gemm_qkvg epilogue -> prep_qkv kernel deleted (and its HBM
// round-trip). Attention kernel unchanged from r5.

#define LOG2E 1.44269504088896340736f

typedef __attribute__((ext_vector_type(4))) float f32x4;
typedef __attribute__((ext_vector_type(8))) short bf16x8;   // 8 x bf16 (4 VGPRs)

__device__ __forceinline__ float bf2f(unsigned short u) {
  union { unsigned u; float f; } x; x.u = ((unsigned)u) << 16; return x.f;
}
__device__ __forceinline__ unsigned short f2bf(float f) {
  union { float f; unsigned u; } x; x.f = f;
  unsigned r = x.u + 0x7fffu + ((x.u >> 16) & 1u);   // RNE
  return (unsigned short)(r >> 16);
}

// async global->LDS, 16B per lane. LDS dest = wave-uniform base + lane*16.
__device__ __forceinline__ void async16(void* lds, const void* g) {
  __builtin_amdgcn_global_load_lds(
      (const __attribute__((address_space(1))) unsigned*)g,
      (__attribute__((address_space(3))) unsigned*)lds, 16, 0, 0);
}
__device__ __forceinline__ void lds_fence() {
  __asm__ volatile("s_waitcnt lgkmcnt(0)" ::: "memory");
}

// ---------------------------------------------------------- fused cvt kernel
__global__ __launch_bounds__(256) void cvt_all(
    const float* __restrict__ s0, const float* __restrict__ s1,
    const float* __restrict__ s2, const float* __restrict__ s3,
    const float* __restrict__ s4, const float* __restrict__ s5,
    unsigned short* __restrict__ d0, unsigned short* __restrict__ d1,
    unsigned short* __restrict__ d2, unsigned short* __restrict__ d3,
    unsigned short* __restrict__ d4, unsigned short* __restrict__ d5) {
  long i = (long)blockIdx.x * 256 + threadIdx.x;   // f4 index
  const float* s; unsigned short* d; long off;
  if      (i < 2097152) { s = s0; d = d0; off = 0; }
  else if (i < 3145728) { s = s1; d = d1; off = 2097152; }
  else if (i < 3276800) { s = s2; d = d2; off = 3145728; }
  else if (i < 3407872) { s = s3; d = d3; off = 3276800; }
  else if (i < 4456448) { s = s4; d = d4; off = 3407872; }
  else                  { s = s5; d = d5; off = 4456448; }
  long j = i - off;
  float4 v = reinterpret_cast<const float4*>(s)[j];
  ushort4 u;
  u.x = f2bf(v.x); u.y = f2bf(v.y); u.z = f2bf(v.z); u.w = f2bf(v.w);
  reinterpret_cast<ushort4*>(d)[j] = u;
}

// ----------------------------------------------------------- GEMM main loop
// acc[4][4] = A[m0:m0+128, :K] @ W[n0:n0+128, :K]^T for this block's 4 waves.
// LDS rows are 32 elems (4 x 16B chunks); chunk c of row r stored at
// phys = c ^ ((r>>1)&3)  -> fragment reads are 2-way (free) instead of 8-way.
__device__ __forceinline__ void gemm_main(
    const unsigned short* __restrict__ A, const unsigned short* __restrict__ W,
    int m0, int n0, int K, unsigned short* As, unsigned short* Bs,
    f32x4 acc[4][4]) {
  const int tid = threadIdx.x;
  const int w = tid >> 6, l = tid & 63, quad = l >> 4, l16 = l & 15;
  const int wm = (w & 1) * 64, wn = (w >> 1) * 64;

  const f32x4 Z4 = {0.f, 0.f, 0.f, 0.f};
#pragma unroll
  for (int i = 0; i < 4; i++)
#pragma unroll
    for (int j = 0; j < 4; j++) acc[i][j] = Z4;

  const int srow = tid >> 2;                              // 0..63
  const int scol = (((tid & 3) ^ ((tid >> 3) & 3))) * 8;  // swizzled src chunk
  const unsigned short* gA = A + (size_t)(m0 + srow) * K + scol;
  const unsigned short* gB = W + (size_t)(n0 + srow) * K + scol;
  unsigned short* lA = As + tid * 8;    // byte offset tid*16
  unsigned short* lB = Bs + tid * 8;
  const int fsw = (quad ^ ((l16 >> 1) & 3)) * 8;          // fragment chunk

  for (int kb = 0; kb < K; kb += 32) {
    async16(lA,        gA + kb);
    async16(lA + 2048, gA + (size_t)64 * K + kb);
    async16(lB,        gB + kb);
    async16(lB + 2048, gB + (size_t)64 * K + kb);
    __syncthreads();   // waits vmcnt(0): async LDS writes landed

    bf16x8 af[4], bf[4];
#pragma unroll
    for (int mt = 0; mt < 4; mt++)
      af[mt] = *(const bf16x8*)&As[(wm + mt * 16 + l16) * 32 + fsw];
#pragma unroll
    for (int nt = 0; nt < 4; nt++)
      bf[nt] = *(const bf16x8*)&Bs[(wn + nt * 16 + l16) * 32 + fsw];
#pragma unroll
    for (int mt = 0; mt < 4; mt++)
#pragma unroll
      for (int nt = 0; nt < 4; nt++)
        acc[mt][nt] = __builtin_amdgcn_mfma_f32_16x16x32_bf16(
            af[mt], bf[nt], acc[mt][nt], 0, 0, 0);
    __syncthreads();   // all reads done before next tile's staging
  }
}

// --------------------------------------- fused QKVG GEMM + RMSNorm/RoPE/T
// ny 0..15: Q -> RMSNorm+RoPE, scale 1/8, write Qn[b][h][s][d]
// ny 16..17: K -> RMSNorm+RoPE, scale LOG2E, write Kn[b][kv][s][d]
// ny 18..19: V -> transpose-scatter to Vt[b][kv][d][s]
// ny 20..35: G -> plain bf16 store to gate[token][2048]
__global__ __launch_bounds__(256) void gemm_qkvg(
    const unsigned short* __restrict__ X,
    const unsigned short* __restrict__ Wq, const unsigned short* __restrict__ Wk,
    const unsigned short* __restrict__ Wv, const unsigned short* __restrict__ Wg,
    const float* __restrict__ cosb, const float* __restrict__ sinb,
    const float* __restrict__ qg, const float* __restrict__ kg,
    unsigned short* __restrict__ Qn, unsigned short* __restrict__ Kn,
    unsigned short* __restrict__ Vt, unsigned short* __restrict__ gate) {
  __shared__ __attribute__((aligned(16))) unsigned short As[128 * 32];
  __shared__ __attribute__((aligned(16))) unsigned short Bs[128 * 32];
  const int ny = blockIdx.y;
  const unsigned short* W; int n0, type;
  if (ny < 16)      { W = Wq; n0 = ny * 128;        type = 0; }
  else if (ny < 18) { W = Wk; n0 = (ny - 16) * 128; type = 1; }
  else if (ny < 20) { W = Wv; n0 = (ny - 18) * 128; type = 2; }
  else              { W = Wg; n0 = (ny - 20) * 128; type = 3; }
  const int m0 = blockIdx.x * 128;

  f32x4 acc[4][4];
  gemm_main(X, W, m0, n0, 2048, As, Bs, acc);

  const int tid = threadIdx.x;
  const int w = tid >> 6, l = tid & 63, quad = l >> 4, l16 = l & 15;
  const int wm = (w & 1) * 64, wn = (w >> 1) * 64;

  if (type == 3) {          // gate: plain bf16 store
#pragma unroll
    for (int mt = 0; mt < 4; mt++)
#pragma unroll
      for (int r = 0; r < 4; r++) {
        int row = m0 + wm + mt * 16 + quad * 4 + r;
#pragma unroll
        for (int nt = 0; nt < 4; nt++)
          gate[(size_t)row * 2048 + n0 + wn + nt * 16 + l16] =
              f2bf(acc[mt][nt][r]);
      }
    return;
  }
  if (type == 2) {          // V: transpose-scatter to Vt[b][kv][d][s]
#pragma unroll
    for (int mt = 0; mt < 4; mt++)
#pragma unroll
      for (int r = 0; r < 4; r++) {
        int row = m0 + wm + mt * 16 + quad * 4 + r;
        int b = row >> 11, s = row & 2047;
#pragma unroll
        for (int nt = 0; nt < 4; nt++) {
          int col = n0 + wn + nt * 16 + l16;
          int kvh = col >> 6, d = col & 63;
          Vt[((size_t)(b * 4 + kvh) * 64 + d) * 2048 + s] =
              f2bf(acc[mt][nt][r]);
        }
      }
    return;
  }

  // Q/K: RMSNorm (f32 acc) + RoPE + scale, transposed store
  const float* gamma = (type == 0) ? qg : kg;
  const float scale  = (type == 0) ? 0.125f : LOG2E;
  const int hb = (n0 + wn) >> 6;     // head index for this wave's 64-col span
  float gv[4];
#pragma unroll
  for (int nt = 0; nt < 4; nt++) gv[nt] = gamma[nt * 16 + l16];

#pragma unroll
  for (int mt = 0; mt < 4; mt++)
#pragma unroll
    for (int r = 0; r < 4; r++) {
      int row = m0 + wm + mt * 16 + quad * 4 + r;
      float ss = 0.f;
#pragma unroll
      for (int nt = 0; nt < 4; nt++) {
        float v = acc[mt][nt][r]; ss += v * v;
      }
#pragma unroll
      for (int off = 1; off < 16; off <<= 1) ss += __shfl_xor(ss, off);
      float rr = rsqrtf(ss * (1.0f / 64.0f) + 1e-6f);
      float xn[4];
#pragma unroll
      for (int nt = 0; nt < 4; nt++) xn[nt] = acc[mt][nt][r] * rr * gv[nt];
      int b = row >> 11, s = row & 2047;
      unsigned short* dst = (type == 0)
          ? Qn + ((size_t)(b * 32 + hb) * 2048 + s) * 64
          : Kn + ((size_t)(b * 4 + hb) * 2048 + s) * 64;
#pragma unroll
      for (int nt = 0; nt < 4; nt++) {
        int d = nt * 16 + l16;
        float rot = (nt < 2) ? -xn[nt ^ 2] : xn[nt ^ 2];
        float cv = cosb[(size_t)row * 64 + d];
        float sv = sinb[(size_t)row * 64 + d];
        dst[d] = f2bf((xn[nt] * cv + rot * sv) * scale);
      }
    }
}

// -------------------------------------------------------------- output GEMM
__global__ __launch_bounds__(256) void gemm_out_k(
    const unsigned short* __restrict__ A, const unsigned short* __restrict__ W,
    float* __restrict__ C) {
  __shared__ __attribute__((aligned(16))) unsigned short As[128 * 32];
  __shared__ __attribute__((aligned(16))) unsigned short Bs[128 * 32];
  const int m0 = blockIdx.x * 128, n0 = blockIdx.y * 128;
  f32x4 acc[4][4];
  gemm_main(A, W, m0, n0, 2048, As, Bs, acc);
  const int tid = threadIdx.x;
  const int w = tid >> 6, l = tid & 63, quad = l >> 4, l16 = l & 15;
  const int wm = (w & 1) * 64, wn = (w >> 1) * 64;
#pragma unroll
  for (int mt = 0; mt < 4; mt++)
#pragma unroll
    for (int nt = 0; nt < 4; nt++) {
      int row = m0 + wm + mt * 16 + quad * 4;
      int col = n0 + wn + nt * 16 + l16;
#pragma unroll
      for (int r = 0; r < 4; r++)
        C[(size_t)(row + r) * 2048 + col] = acc[mt][nt][r];
    }
}

// ---------------------------------------------------------- flash attention
// (unchanged from r5)
__global__ __launch_bounds__(256, 4) void attn(
    const unsigned short* __restrict__ Qn, const unsigned short* __restrict__ Kn,
    const unsigned short* __restrict__ Vt, const unsigned short* __restrict__ gate,
    unsigned short* __restrict__ act) {
  __shared__ __attribute__((aligned(16))) unsigned short smem[20480];  // 40 KB
  unsigned short* Ps = smem + 16384;    // 4 x [32 q][32 kv] = 8 KB

  const int tid = threadIdx.x, w = tid >> 6, l = tid & 63;
  const int quad = l >> 4, l16 = l & 15, l7 = l16 & 7;
  const int bh = blockIdx.y, b = bh >> 5, h = bh & 31, kvh = h >> 3;
  const int q0 = blockIdx.x * 128;

  const unsigned short* Qg = Qn + ((size_t)(b * 32 + h) * 2048 + q0) * 64;
  const unsigned short* Kg = Kn + (size_t)(b * 4 + kvh) * 2048 * 64;
  const unsigned short* Vg = Vt + (size_t)(b * 4 + kvh) * 64 * 2048;
  unsigned short* Pw = Ps + w * 1024;   // wave-private [32 q][32 kv]

  const int kq_src = ((tid & 7) ^ ((tid >> 3) & 7)) * 8;

  // ---- prologue: stage Q [128][64] into smem[0..8192), read q-fragments
#pragma unroll
  for (int i = 0; i < 4; i++)
    async16(smem + i * 2048 + tid * 8,
            Qg + (size_t)(i * 32 + (tid >> 3)) * 64 + kq_src);
  __syncthreads();
  bf16x8 qf[2][2];
#pragma unroll
  for (int mt = 0; mt < 2; mt++)
#pragma unroll
    for (int ks = 0; ks < 2; ks++) {
      int row = w * 32 + mt * 16 + l16;           // row&7 == l7
      qf[mt][ks] = *(const bf16x8*)&smem[row * 64 + ((ks * 4 + quad) ^ l7) * 8];
    }
  __syncthreads();   // Q region free for K/V staging

  const f32x4 Z4 = {0.f, 0.f, 0.f, 0.f};
  f32x4 O[2][4];
  float lp[2][4];
#pragma unroll
  for (int mt = 0; mt < 2; mt++) {
#pragma unroll
    for (int nt = 0; nt < 4; nt++) O[mt][nt] = Z4;
#pragma unroll
    for (int r = 0; r < 4; r++) lp[mt][r] = 0.f;
  }

  // stage tile 0 into buf0
#pragma unroll
  for (int i = 0; i < 2; i++) {
    async16(smem + i * 2048 + tid * 8,
            Kg + (size_t)(i * 32 + (tid >> 3)) * 64 + kq_src);
    async16(smem + 4096 + i * 2048 + tid * 8,
            Vg + (size_t)(i * 32 + (tid >> 3)) * 2048 + kq_src);
  }

  for (int kt = 0; kt < 32; kt++) {
    __syncthreads();   // drains stage(kt); all waves past compute(kt-1)

    if (kt < 31) {     // stage tile kt+1 into the other buffer (overlapped)
      unsigned short* nb = smem + ((kt + 1) & 1) * 8192;
      const int s1 = (kt + 1) * 64;
#pragma unroll
      for (int i = 0; i < 2; i++) {
        async16(nb + i * 2048 + tid * 8,
                Kg + (size_t)(s1 + i * 32 + (tid >> 3)) * 64 + kq_src);
        async16(nb + 4096 + i * 2048 + tid * 8,
                Vg + (size_t)(i * 32 + (tid >> 3)) * 2048 + s1 + kq_src);
      }
    }

    unsigned short* Ks  = smem + (kt & 1) * 8192;
    unsigned short* Vts = Ks + 4096;

    // ---- S = Q K^T over this kv-64 tile
    f32x4 sc[2][4];
#pragma unroll
    for (int mt = 0; mt < 2; mt++)
#pragma unroll
      for (int nt = 0; nt < 4; nt++) sc[mt][nt] = Z4;
#pragma unroll
    for (int nt = 0; nt < 4; nt++) {
      int row = nt * 16 + l16;                    // row&7 == l7
      bf16x8 kf0 = *(const bf16x8*)&Ks[row * 64 + (quad ^ l7) * 8];
      bf16x8 kf1 = *(const bf16x8*)&Ks[row * 64 + ((4 + quad) ^ l7) * 8];
#pragma unroll
      for (int mt = 0; mt < 2; mt++) {
        sc[mt][nt] = __builtin_amdgcn_mfma_f32_16x16x32_bf16(qf[mt][0], kf0, sc[mt][nt], 0, 0, 0);
        sc[mt][nt] = __builtin_amdgcn_mfma_f32_16x16x32_bf16(qf[mt][1], kf1, sc[mt][nt], 0, 0, 0);
      }
    }

    // ---- softmax + PV in two kv-32 sub-chunks through wave-private Ps
#pragma unroll
    for (int ks2 = 0; ks2 < 2; ks2++) {
#pragma unroll
      for (int mt = 0; mt < 2; mt++)
#pragma unroll
        for (int ntl = 0; ntl < 2; ntl++) {
          int nt = ks2 * 2 + ntl;
#pragma unroll
          for (int r = 0; r < 4; r++) {
            float p = __builtin_amdgcn_exp2f(sc[mt][nt][r]);
            union { float f; unsigned u; } x; x.f = p;
            union { unsigned u; float f; } t; t.u = x.u & 0xffff0000u;
            lp[mt][r] += t.f;
            int q = mt * 16 + quad * 4 + r;
            int c = ntl * 2 + (l16 >> 3);
            int phys = c ^ ((q >> 1) & 3);
            Pw[q * 32 + phys * 8 + l7] = (unsigned short)(x.u >> 16);
          }
        }
      lds_fence();   // P writes visible before reads (same wave)

      bf16x8 pf[2];
#pragma unroll
      for (int mt = 0; mt < 2; mt++) {
        int q = mt * 16 + l16;
        int phys = quad ^ ((l16 >> 1) & 3);
        pf[mt] = *(const bf16x8*)&Pw[q * 32 + phys * 8];
      }
#pragma unroll
      for (int nt2 = 0; nt2 < 4; nt2++) {
        int d = nt2 * 16 + l16;                   // d&7 == l7
        bf16x8 vf = *(const bf16x8*)&Vts[d * 64 + ((ks2 * 4 + quad) ^ l7) * 8];
#pragma unroll
        for (int mt = 0; mt < 2; mt++)
          O[mt][nt2] = __builtin_amdgcn_mfma_f32_16x16x32_bf16(
              pf[mt], vf, O[mt][nt2], 0, 0, 0);
      }
      lds_fence();   // sub-chunk reads retired before next sub-chunk writes
    }
  }

  // ---- final l reduction across the 16-lane column groups (once)
#pragma unroll
  for (int mt = 0; mt < 2; mt++)
#pragma unroll
    for (int r = 0; r < 4; r++) {
      float s = lp[mt][r];
#pragma unroll
      for (int off = 1; off < 16; off <<= 1) s += __shfl_xor(s, off);
      lp[mt][r] = s;
    }

  // ---- epilogue: O/l * sigmoid(gate) -> act[b][s][h*64+d]
#pragma unroll
  for (int mt = 0; mt < 2; mt++) {
    float inv[4];
#pragma unroll
    for (int r = 0; r < 4; r++) inv[r] = 1.0f / lp[mt][r];
#pragma unroll
    for (int nt = 0; nt < 4; nt++)
#pragma unroll
      for (int r = 0; r < 4; r++) {
        int srow = q0 + w * 32 + mt * 16 + quad * 4 + r;
        int col = h * 64 + nt * 16 + l16;
        size_t off = (size_t)(b * 2048 + srow) * 2048 + col;
        float g = bf2f(gate[off]);
        float sig = 1.0f / (1.0f + __builtin_amdgcn_exp2f(-g * LOG2E));
        act[off] = f2bf(O[mt][nt][r] * inv[r] * sig);
      }
  }
}

// ------------------------------------------------------------------ launcher
extern "C" void kernel_launch(void* const* d_in, const int* in_sizes, int n_in,
                              void* d_out, int out_size, void* d_ws, size_t ws_size,
                              hipStream_t stream) {
  const float* hid  = (const float*)d_in[0];
  const float* cosb = (const float*)d_in[1];
  const float* sinb = (const float*)d_in[2];
  const float* Wq   = (const float*)d_in[3];
  const float* Wk   = (const float*)d_in[4];
  const float* Wv   = (const float*)d_in[5];
  const float* Wg   = (const float*)d_in[6];
  const float* Wo   = (const float*)d_in[7];
  const float* qg   = (const float*)d_in[8];
  const float* kg   = (const float*)d_in[9];
  float* out = (float*)d_out;

  char* ws = (char*)d_ws;
  unsigned short* Xb   = (unsigned short*)(ws);              // 16,777,216 B
  unsigned short* WqB  = (unsigned short*)(ws + 16777216);   //  8,388,608
  unsigned short* WkB  = (unsigned short*)(ws + 25165824);   //  1,048,576
  unsigned short* WvB  = (unsigned short*)(ws + 26214400);   //  1,048,576
  unsigned short* WgB  = (unsigned short*)(ws + 27262976);   //  8,388,608
  unsigned short* WoB  = (unsigned short*)(ws + 35651584);   //  8,388,608
  unsigned short* gate = (unsigned short*)(ws + 44040192);   // 16,777,216
  unsigned short* Qn   = (unsigned short*)(ws + 60817408);   // 16,777,216
  unsigned short* Kn   = (unsigned short*)(ws + 77594624);   //  2,097,152
  unsigned short* Vt   = (unsigned short*)(ws + 79691776);   //  2,097,152
  // region reuse: act overlays WqB..WgB (18 MB, dead after gemm_qkvg)
  unsigned short* act = WqB;

  cvt_all<<<dim3(21504), dim3(256), 0, stream>>>(
      hid, Wq, Wk, Wv, Wg, Wo, Xb, WqB, WkB, WvB, WgB, WoB);

  gemm_qkvg<<<dim3(32, 36), dim3(256), 0, stream>>>(
      Xb, WqB, WkB, WvB, WgB, cosb, sinb, qg, kg, Qn, Kn, Vt, gate);

  attn<<<dim3(16, 64), dim3(256), 0, stream>>>(Qn, Kn, Vt, gate, act);

  gemm_out_k<<<dim3(32, 16), dim3(256), 0, stream>>>(act, WoB, out);
}